// Round 6
// baseline (420.465 us; speedup 1.0000x reference)
//
#include <hip/hip_runtime.h>

#define LOG2E 1.44269504088896340736f

typedef float v4f __attribute__((ext_vector_type(4)));

struct Params {
  const float* x[4]; const float* f[4]; const float* kvw[4]; const float* kvb[4];
  const float* pw[4]; const float* pb[4]; const float* g[4]; const float* lb[4];
  float* kb[4]; float* ob[4]; float* out[4];
};

__device__ inline v4f fmav(v4f a, v4f b, v4f c) { return a * b + c; }

// ---------------- KV projection: packed layout kb[head][key][0:16]=K, [16:32]=V ----------------
__global__ __launch_bounds__(256) void kv_all(Params P) {
  int bid = blockIdx.x;
  int s, local;
  if (bid < 8)       { s = 0; local = bid; }
  else if (bid < 24) { s = 1; local = bid - 8; }
  else if (bid < 56) { s = 2; local = bid - 24; }
  else               { s = 3; local = bid - 56; }
  const int C = 32 << s;
  int nt = local & 7, jt = local >> 3;
  int n0 = nt * 64, j0 = jt * 64;
  const float* __restrict__ f = P.f[s];
  const float* __restrict__ w = P.kvw[s];
  __shared__ float fa[64][17];
  __shared__ float wb[64][17];
  int t = threadIdx.x;
  int ti = t & 15, tj = t >> 4;
  float acc[4][4];
  #pragma unroll
  for (int a = 0; a < 4; a++)
    #pragma unroll
    for (int b = 0; b < 4; b++) acc[a][b] = 0.f;

  for (int k0 = 0; k0 < C; k0 += 16) {
    __syncthreads();
    for (int i = t; i < 1024; i += 256) {
      int r = i >> 4, kk = i & 15;
      fa[r][kk] = f[(n0 + r) * C + k0 + kk];
      wb[r][kk] = w[(j0 + r) * C + k0 + kk];
    }
    __syncthreads();
    #pragma unroll
    for (int kk = 0; kk < 16; ++kk) {
      float av[4], bv[4];
      #pragma unroll
      for (int ii = 0; ii < 4; ii++) av[ii] = fa[ti * 4 + ii][kk];
      #pragma unroll
      for (int jj = 0; jj < 4; jj++) bv[jj] = wb[tj * 4 + jj][kk];
      #pragma unroll
      for (int ii = 0; ii < 4; ii++)
        #pragma unroll
        for (int jj = 0; jj < 4; jj++)
          acc[ii][jj] = fmaf(av[ii], bv[jj], acc[ii][jj]);
    }
  }
  const float* __restrict__ bias = P.kvb[s];
  float* kb = P.kb[s];
  #pragma unroll
  for (int ii = 0; ii < 4; ii++) {
    int n = n0 + ti * 4 + ii;
    #pragma unroll
    for (int jj = 0; jj < 4; jj++) {
      int j = j0 + tj * 4 + jj;
      float val = acc[ii][jj] + bias[j];
      if (j < C) {
        kb[(j >> 4) * 16384 + n * 32 + (j & 15)] = val;          // K slot
      } else {
        int j2 = j - C;
        kb[(j2 >> 4) * 16384 + n * 32 + 16 + (j2 & 15)] = val;   // V slot
      }
    }
  }
}

// ---------------- Attention: wave-uniform K/V loads straight from global (no LDS, no barriers) ----------------
// Each key's 128B packed K|V row has a block-uniform address -> scalar/coalesced load path,
// bypassing the LDS pipe that bounded rounds 1-5. K/V (832KB total) is L2-resident.
template <int C, int H>
__device__ void attn_stage(const float* __restrict__ kb, const float* __restrict__ x,
                           float* __restrict__ ob, int local) {
  constexpr int ROWS = 2 * ((C == 32) ? 32768 : (C == 64) ? 4096 : (C == 128) ? 512 : 64);
  int tile = local / H, head = local % H;
  const float* __restrict__ kvh = kb + head * 16384;  // 512 keys * 32 floats (K|V packed)
  int t = threadIdx.x;
  int row = tile * 256 + t;
  bool valid = row < ROWS;
  int rc = valid ? row : (ROWS - 1);

  const v4f* xr = (const v4f*)(x + (size_t)rc * C + head * 16);
  const float qs = 0.25f * LOG2E;  // head_dim^-0.5 folded with log2(e)
  v4f q0 = xr[0] * qs, q1 = xr[1] * qs, q2 = xr[2] * qs, q3 = xr[3] * qs;

  float m = -1e30f, l = 0.f;
  v4f a0 = 0.f, a1 = 0.f, a2 = 0.f, a3 = 0.f;

  #pragma unroll 2
  for (int key = 0; key < 512; ++key) {
    const v4f* kr = (const v4f*)(kvh + key * 32);   // block-uniform address
    v4f k0 = kr[0], k1 = kr[1], k2 = kr[2], k3 = kr[3];
    v4f tv = q0 * k0; tv = fmav(q1, k1, tv); tv = fmav(q2, k2, tv); tv = fmav(q3, k3, tv);
    float sc = (tv.x + tv.y) + (tv.z + tv.w);       // score in log2 units
    if (__any(sc > m + 8.f)) {                      // defer-max: rare after first keys
      float mn = fmaxf(m, sc);
      float r = __builtin_amdgcn_exp2f(m - mn);
      l *= r; a0 *= r; a1 *= r; a2 *= r; a3 *= r; m = mn;
    }
    float p = __builtin_amdgcn_exp2f(sc - m);
    l += p;
    v4f v0 = kr[4], v1 = kr[5], v2 = kr[6], v3 = kr[7];
    a0 = fmav(p, v0, a0); a1 = fmav(p, v1, a1);
    a2 = fmav(p, v2, a2); a3 = fmav(p, v3, a3);
  }

  if (valid) {
    float inv = 1.f / l;
    v4f* o = (v4f*)(ob + (size_t)row * C + head * 16);
    o[0] = a0 * inv; o[1] = a1 * inv; o[2] = a2 * inv; o[3] = a3 * inv;
  }
}

__global__ __launch_bounds__(256) void attn_all(
    const float* __restrict__ kb0, const float* __restrict__ kb1,
    const float* __restrict__ kb2, const float* __restrict__ kb3,
    const float* __restrict__ x0, const float* __restrict__ x1,
    const float* __restrict__ x2, const float* __restrict__ x3,
    float* __restrict__ ob0, float* __restrict__ ob1,
    float* __restrict__ ob2, float* __restrict__ ob3) {
  int bid = blockIdx.x;
  if (bid < 512)      attn_stage<32, 2>(kb0, x0, ob0, bid);
  else if (bid < 640) attn_stage<64, 4>(kb1, x1, ob1, bid - 512);
  else if (bid < 672) attn_stage<128, 8>(kb2, x2, ob2, bid - 640);
  else                attn_stage<256, 16>(kb3, x3, ob3, bid - 672);
}

// ---------------- Passthrough copies (replaces SDMA memcpy nodes) ----------------
__global__ __launch_bounds__(256) void copy_pass(const float4* __restrict__ x4,
                                                 const float4* __restrict__ x5,
                                                 float4* __restrict__ o) {
  int i = blockIdx.x * 256 + threadIdx.x;
  if (i < 1280)      o[i] = x4[i];
  else if (i < 1440) o[i] = x5[i - 1280];
}

// ---------------- Proj + residual + LayerNorm: RB=2048/C rows per block, ~9 KB LDS ----------------
template <int C>
__device__ void proj_stage(const Params& P, int s, int tile, float* olds) {
  constexpr int CP = C + 4;      // +4 floats keeps 16B alignment, breaks bank aliasing
  constexpr int R = 256 / C;     // row-groups per pass
  constexpr int NR = 8;          // rows per thread
  constexpr int RB = 2048 / C;   // rows per block
  int r0 = tile * RB;
  int t = threadIdx.x;
  const float4* __restrict__ obv = (const float4*)(P.ob[s] + (size_t)r0 * C);
  for (int i = t; i < 512; i += 256) {
    int row = i / (C / 4), kk = i % (C / 4);
    ((float4*)(olds + row * CP))[kk] = obv[i];
  }
  __syncthreads();
  int j = t % C, rg = t / C;
  const float* __restrict__ pw = P.pw[s];
  float acc[NR];
  #pragma unroll
  for (int i = 0; i < NR; ++i) acc[i] = 0.f;
  for (int k = 0; k < C; k += 4) {
    float4 w4 = *(const float4*)(pw + (size_t)j * C + k);
    #pragma unroll
    for (int i = 0; i < NR; ++i) {
      float4 o4 = *(const float4*)(olds + (rg + i * R) * CP + k);
      acc[i] = fmaf(o4.x, w4.x, acc[i]);
      acc[i] = fmaf(o4.y, w4.y, acc[i]);
      acc[i] = fmaf(o4.z, w4.z, acc[i]);
      acc[i] = fmaf(o4.w, w4.w, acc[i]);
    }
  }
  __syncthreads();  // all proj reads of olds done
  float pbj = P.pb[s][j];
  const float* __restrict__ x = P.x[s];
  #pragma unroll
  for (int i = 0; i < NR; ++i) {
    int r = rg + i * R;
    float xv = x[(size_t)(r0 + r) * C + j];
    olds[r * CP + j] = 0.5f * (acc[i] + pbj) + 0.5f * xv;
  }
  __syncthreads();
  // LayerNorm: one wave handles RB/4 rows
  int lane = t & 63, wv = t >> 6;
  const float* __restrict__ g = P.g[s];
  const float* __restrict__ lb = P.lb[s];
  float* __restrict__ out = P.out[s];
  #pragma unroll
  for (int rr = 0; rr < RB / 4; ++rr) {
    int r = wv * (RB / 4) + rr;
    float sum = 0.f, sq = 0.f;
    #pragma unroll
    for (int ch = lane; ch < C; ch += 64) {
      float v = olds[r * CP + ch];
      sum += v; sq = fmaf(v, v, sq);
    }
    #pragma unroll
    for (int o = 32; o; o >>= 1) { sum += __shfl_xor(sum, o); sq += __shfl_xor(sq, o); }
    float mu = sum * (1.f / C);
    float var = sq * (1.f / C) - mu * mu;
    float rstd = rsqrtf(var + 1e-5f);
    #pragma unroll
    for (int ch = lane; ch < C; ch += 64) {
      float v = (olds[r * CP + ch] - mu) * rstd;
      out[(size_t)(r0 + r) * C + ch] = fmaf(v, g[ch], lb[ch]);
    }
  }
}

__global__ __launch_bounds__(256) void proj_ln_all(Params P) {
  __shared__ float olds[2304];  // max over stages: RB*(C+4) floats
  int bid = blockIdx.x;
  if (bid < 1024)      proj_stage<32>(P, 0, bid, olds);
  else if (bid < 1280) proj_stage<64>(P, 1, bid - 1024, olds);
  else if (bid < 1344) proj_stage<128>(P, 2, bid - 1280, olds);
  else                 proj_stage<256>(P, 3, bid - 1344, olds);
}

extern "C" void kernel_launch(void* const* d_in, const int* in_sizes, int n_in,
                              void* d_out, int out_size, void* d_ws, size_t ws_size,
                              hipStream_t stream) {
  Params P;
  float* ws = (float*)d_ws;
  float* out = (float*)d_out;
  // ws layout (floats): packed K|V per stage, then attention-output buffers
  const size_t kvoff[4]  = {0, 32768, 98304, 229376};
  const size_t ooff[4]   = {491520, 2588672, 3112960, 3244032};
  const size_t outoff[4] = {0, 2097152, 2621440, 2752512};
  for (int i = 0; i < 4; ++i) {
    const int b = i * 8;
    P.x[i]   = (const float*)d_in[b + 0];
    P.f[i]   = (const float*)d_in[b + 1];
    P.kvw[i] = (const float*)d_in[b + 2];
    P.kvb[i] = (const float*)d_in[b + 3];
    P.pw[i]  = (const float*)d_in[b + 4];
    P.pb[i]  = (const float*)d_in[b + 5];
    P.g[i]   = (const float*)d_in[b + 6];
    P.lb[i]  = (const float*)d_in[b + 7];
    P.kb[i]  = ws + kvoff[i];
    P.ob[i]  = ws + ooff[i];
    P.out[i] = out + outoff[i];
  }

  copy_pass<<<6, 256, 0, stream>>>((const float4*)d_in[32], (const float4*)d_in[33],
                                   (float4*)(out + 2785280));
  kv_all<<<120, 256, 0, stream>>>(P);
  attn_all<<<688, 256, 0, stream>>>(P.kb[0], P.kb[1], P.kb[2], P.kb[3],
                                    P.x[0], P.x[1], P.x[2], P.x[3],
                                    P.ob[0], P.ob[1], P.ob[2], P.ob[3]);
  proj_ln_all<<<1360, 256, 0, stream>>>(P);
}

// Round 7
// 357.312 us; speedup vs baseline: 1.1767x; 1.1767x over previous
//
#include <hip/hip_runtime.h>

#define LOG2E 1.44269504088896340736f
#define RHTOT 174080

typedef float v4f __attribute__((ext_vector_type(4)));

struct Params {
  const float* x[4]; const float* f[4]; const float* kvw[4]; const float* kvb[4];
  const float* pw[4]; const float* pb[4]; const float* g[4]; const float* lb[4];
  float* kb[4]; float* ob[4]; float* out[4];
};

__device__ inline v4f fmav(v4f a, v4f b, v4f c) { return a * b + c; }

// ---------------- KV projection: packed layout kb[head][key][0:16]=K, [16:32]=V ----------------
__global__ __launch_bounds__(256) void kv_all(Params P) {
  int bid = blockIdx.x;
  int s, local;
  if (bid < 8)       { s = 0; local = bid; }
  else if (bid < 24) { s = 1; local = bid - 8; }
  else if (bid < 56) { s = 2; local = bid - 24; }
  else               { s = 3; local = bid - 56; }
  const int C = 32 << s;
  int nt = local & 7, jt = local >> 3;
  int n0 = nt * 64, j0 = jt * 64;
  const float* __restrict__ f = P.f[s];
  const float* __restrict__ w = P.kvw[s];
  __shared__ float fa[64][17];
  __shared__ float wb[64][17];
  int t = threadIdx.x;
  int ti = t & 15, tj = t >> 4;
  float acc[4][4];
  #pragma unroll
  for (int a = 0; a < 4; a++)
    #pragma unroll
    for (int b = 0; b < 4; b++) acc[a][b] = 0.f;

  for (int k0 = 0; k0 < C; k0 += 16) {
    __syncthreads();
    for (int i = t; i < 1024; i += 256) {
      int r = i >> 4, kk = i & 15;
      fa[r][kk] = f[(n0 + r) * C + k0 + kk];
      wb[r][kk] = w[(j0 + r) * C + k0 + kk];
    }
    __syncthreads();
    #pragma unroll
    for (int kk = 0; kk < 16; ++kk) {
      float av[4], bv[4];
      #pragma unroll
      for (int ii = 0; ii < 4; ii++) av[ii] = fa[ti * 4 + ii][kk];
      #pragma unroll
      for (int jj = 0; jj < 4; jj++) bv[jj] = wb[tj * 4 + jj][kk];
      #pragma unroll
      for (int ii = 0; ii < 4; ii++)
        #pragma unroll
        for (int jj = 0; jj < 4; jj++)
          acc[ii][jj] = fmaf(av[ii], bv[jj], acc[ii][jj]);
    }
  }
  const float* __restrict__ bias = P.kvb[s];
  float* kb = P.kb[s];
  #pragma unroll
  for (int ii = 0; ii < 4; ii++) {
    int n = n0 + ti * 4 + ii;
    #pragma unroll
    for (int jj = 0; jj < 4; jj++) {
      int j = j0 + tj * 4 + jj;
      float val = acc[ii][jj] + bias[j];
      if (j < C) {
        kb[(j >> 4) * 16384 + n * 32 + (j & 15)] = val;          // K slot
      } else {
        int j2 = j - C;
        kb[(j2 >> 4) * 16384 + n * 32 + 16 + (j2 & 15)] = val;   // V slot
      }
    }
  }
}

// ---------------- Attention split-K: 2 rows/lane, G key-groups, uniform (scalar-path) K/V loads ----------------
// Partials (m, l, raw acc) per (rowhead, kgroup); rowhead index rh = RHB + head*ROWS + row (head-major).
template <int C, int H, int ROWS, int RHB>
__device__ void attn_stage(const float* __restrict__ kb, const float* __restrict__ x,
                           float* __restrict__ accP, float* __restrict__ mP,
                           float* __restrict__ lP, int local, int G, int KPG) {
  int HG = H * G;
  int tile = local / HG, r2 = local % HG;
  int head = r2 / G, kg = r2 % G;
  int t = threadIdx.x;
  int row0 = tile * 512 + t;
  if (row0 >= ROWS) return;                      // stage-3 tail lanes
  int row1 = row0 + 256;
  bool v1 = row1 < ROWS;
  int rc1 = v1 ? row1 : (ROWS - 1);
  const float* __restrict__ kvh = kb + head * 16384 + (size_t)kg * KPG * 32;

  const float qs = 0.25f * LOG2E;                // head_dim^-0.5 folded with log2(e)
  const v4f* xa = (const v4f*)(x + (size_t)row0 * C + head * 16);
  const v4f* xb = (const v4f*)(x + (size_t)rc1 * C + head * 16);
  v4f qa0 = xa[0]*qs, qa1 = xa[1]*qs, qa2 = xa[2]*qs, qa3 = xa[3]*qs;
  v4f qb0 = xb[0]*qs, qb1 = xb[1]*qs, qb2 = xb[2]*qs, qb3 = xb[3]*qs;

  float ma = -1e30f, la = 0.f, mb = -1e30f, lb = 0.f;
  v4f aa0 = 0.f, aa1 = 0.f, aa2 = 0.f, aa3 = 0.f;
  v4f ab0 = 0.f, ab1 = 0.f, ab2 = 0.f, ab3 = 0.f;

  #pragma unroll 2
  for (int key = 0; key < KPG; ++key) {
    const v4f* kr = (const v4f*)(kvh + (size_t)key * 32);  // block-uniform address
    v4f k0 = kr[0], k1 = kr[1], k2 = kr[2], k3 = kr[3];
    v4f ta = qa0 * k0; ta = fmav(qa1, k1, ta); ta = fmav(qa2, k2, ta); ta = fmav(qa3, k3, ta);
    v4f tb = qb0 * k0; tb = fmav(qb1, k1, tb); tb = fmav(qb2, k2, tb); tb = fmav(qb3, k3, tb);
    float sa = (ta.x + ta.y) + (ta.z + ta.w);    // scores in log2 units
    float sb = (tb.x + tb.y) + (tb.z + tb.w);
    if (__any(fmaxf(sa - ma, sb - mb) > 8.f)) {  // defer-max: rare after first keys
      float mna = fmaxf(ma, sa);
      float ra = __builtin_amdgcn_exp2f(ma - mna);
      la *= ra; aa0 *= ra; aa1 *= ra; aa2 *= ra; aa3 *= ra; ma = mna;
      float mnb = fmaxf(mb, sb);
      float rb = __builtin_amdgcn_exp2f(mb - mnb);
      lb *= rb; ab0 *= rb; ab1 *= rb; ab2 *= rb; ab3 *= rb; mb = mnb;
    }
    float pa = __builtin_amdgcn_exp2f(sa - ma);
    float pb = __builtin_amdgcn_exp2f(sb - mb);
    la += pa; lb += pb;
    v4f v0 = kr[4], v1_ = kr[5], v2 = kr[6], v3 = kr[7];
    aa0 = fmav(pa, v0, aa0); aa1 = fmav(pa, v1_, aa1);
    aa2 = fmav(pa, v2, aa2); aa3 = fmav(pa, v3, aa3);
    ab0 = fmav(pb, v0, ab0); ab1 = fmav(pb, v1_, ab1);
    ab2 = fmav(pb, v2, ab2); ab3 = fmav(pb, v3, ab3);
  }

  size_t rhA = (size_t)RHB + (size_t)head * ROWS + row0;
  size_t kgo = (size_t)kg * RHTOT;
  if (G == 1) {                                  // fallback path: normalize in-place, no combine
    float inv = 1.f / la;
    v4f* d = (v4f*)(accP + rhA * 16);
    d[0] = aa0 * inv; d[1] = aa1 * inv; d[2] = aa2 * inv; d[3] = aa3 * inv;
    if (v1) {
      float invb = 1.f / lb;
      v4f* e = (v4f*)(accP + ((size_t)RHB + (size_t)head * ROWS + row1) * 16);
      e[0] = ab0 * invb; e[1] = ab1 * invb; e[2] = ab2 * invb; e[3] = ab3 * invb;
    }
  } else {
    mP[kgo + rhA] = ma; lP[kgo + rhA] = la;
    v4f* d = (v4f*)(accP + (kgo + rhA) * 16);
    d[0] = aa0; d[1] = aa1; d[2] = aa2; d[3] = aa3;
    if (v1) {
      size_t rhB = (size_t)RHB + (size_t)head * ROWS + row1;
      mP[kgo + rhB] = mb; lP[kgo + rhB] = lb;
      v4f* e = (v4f*)(accP + (kgo + rhB) * 16);
      e[0] = ab0; e[1] = ab1; e[2] = ab2; e[3] = ab3;
    }
  }
}

__global__ __launch_bounds__(256) void attn_split(
    const float* __restrict__ kb0, const float* __restrict__ kb1,
    const float* __restrict__ kb2, const float* __restrict__ kb3,
    const float* __restrict__ x0, const float* __restrict__ x1,
    const float* __restrict__ x2, const float* __restrict__ x3,
    float* __restrict__ accP, float* __restrict__ mP, float* __restrict__ lP,
    int G, int KPG) {
  int bid = blockIdx.x;
  int b0 = 256 * G, b1 = b0 + 64 * G, b2 = b1 + 16 * G;
  if (bid < b0)      attn_stage<32, 2, 65536, 0>(kb0, x0, accP, mP, lP, bid, G, KPG);
  else if (bid < b1) attn_stage<64, 4, 8192, 131072>(kb1, x1, accP, mP, lP, bid - b0, G, KPG);
  else if (bid < b2) attn_stage<128, 8, 1024, 163840>(kb2, x2, accP, mP, lP, bid - b1, G, KPG);
  else               attn_stage<256, 16, 128, 172032>(kb3, x3, accP, mP, lP, bid - b2, G, KPG);
}

// ---------------- Split-K combine: o[rh] = sum_g w_g*acc_g / sum_g w_g*l_g, w_g=2^(m_g-M) ----------------
__global__ __launch_bounds__(256) void combine_k(float* __restrict__ accP,
                                                 const float* __restrict__ mP,
                                                 const float* __restrict__ lP, int G) {
  size_t rh = (size_t)blockIdx.x * 256 + threadIdx.x;
  if (rh >= RHTOT) return;
  float M = mP[rh];
  for (int g = 1; g < G; ++g) M = fmaxf(M, mP[(size_t)g * RHTOT + rh]);
  float lt = 0.f;
  v4f o0 = 0.f, o1 = 0.f, o2 = 0.f, o3 = 0.f;
  for (int g = 0; g < G; ++g) {
    size_t idx = (size_t)g * RHTOT + rh;
    float w = __builtin_amdgcn_exp2f(mP[idx] - M);
    lt = fmaf(w, lP[idx], lt);
    const v4f* a = (const v4f*)(accP + idx * 16);
    o0 = fmav(w, a[0], o0); o1 = fmav(w, a[1], o1);
    o2 = fmav(w, a[2], o2); o3 = fmav(w, a[3], o3);
  }
  float inv = 1.f / lt;
  v4f* d = (v4f*)(accP + rh * 16);
  d[0] = o0 * inv; d[1] = o1 * inv; d[2] = o2 * inv; d[3] = o3 * inv;
}

// ---------------- Passthrough copies (replaces SDMA memcpy nodes) ----------------
__global__ __launch_bounds__(256) void copy_pass(const float4* __restrict__ x4,
                                                 const float4* __restrict__ x5,
                                                 float4* __restrict__ o) {
  int i = blockIdx.x * 256 + threadIdx.x;
  if (i < 1280)      o[i] = x4[i];
  else if (i < 1440) o[i] = x5[i - 1280];
}

// ---------------- Proj + residual + LayerNorm (o input is head-major [head][ROWS][16]) ----------------
template <int C, int ROWS>
__device__ void proj_stage(const Params& P, int s, int tile, float* olds) {
  constexpr int CP = C + 4;      // +4 floats keeps 16B alignment, breaks bank aliasing
  constexpr int R = 256 / C;     // row-groups per pass
  constexpr int NR = 8;          // rows per thread
  constexpr int RB = 2048 / C;   // rows per block
  constexpr int RB4 = RB * 4;
  int r0 = tile * RB;
  int t = threadIdx.x;
  const float4* __restrict__ ob4 = (const float4*)P.ob[s];  // per-stage slice, [head][ROWS][16]
  for (int i = t; i < 512; i += 256) {
    int h = i / RB4, rem = i % RB4;
    int row = rem >> 2, d4 = rem & 3;
    float4 v = ob4[((size_t)h * ROWS + r0 + row) * 4 + d4];
    ((float4*)(olds + row * CP + h * 16))[d4] = v;
  }
  __syncthreads();
  int j = t % C, rg = t / C;
  const float* __restrict__ pw = P.pw[s];
  float acc[NR];
  #pragma unroll
  for (int i = 0; i < NR; ++i) acc[i] = 0.f;
  for (int k = 0; k < C; k += 4) {
    float4 w4 = *(const float4*)(pw + (size_t)j * C + k);
    #pragma unroll
    for (int i = 0; i < NR; ++i) {
      float4 o4 = *(const float4*)(olds + (rg + i * R) * CP + k);
      acc[i] = fmaf(o4.x, w4.x, acc[i]);
      acc[i] = fmaf(o4.y, w4.y, acc[i]);
      acc[i] = fmaf(o4.z, w4.z, acc[i]);
      acc[i] = fmaf(o4.w, w4.w, acc[i]);
    }
  }
  __syncthreads();  // all proj reads of olds done
  float pbj = P.pb[s][j];
  const float* __restrict__ x = P.x[s];
  #pragma unroll
  for (int i = 0; i < NR; ++i) {
    int r = rg + i * R;
    float xv = x[(size_t)(r0 + r) * C + j];
    olds[r * CP + j] = 0.5f * (acc[i] + pbj) + 0.5f * xv;
  }
  __syncthreads();
  // LayerNorm: one wave handles RB/4 rows
  int lane = t & 63, wv = t >> 6;
  const float* __restrict__ g = P.g[s];
  const float* __restrict__ lb = P.lb[s];
  float* __restrict__ out = P.out[s];
  #pragma unroll
  for (int rr = 0; rr < RB / 4; ++rr) {
    int r = wv * (RB / 4) + rr;
    float sum = 0.f, sq = 0.f;
    #pragma unroll
    for (int ch = lane; ch < C; ch += 64) {
      float v = olds[r * CP + ch];
      sum += v; sq = fmaf(v, v, sq);
    }
    #pragma unroll
    for (int o = 32; o; o >>= 1) { sum += __shfl_xor(sum, o); sq += __shfl_xor(sq, o); }
    float mu = sum * (1.f / C);
    float var = sq * (1.f / C) - mu * mu;
    float rstd = rsqrtf(var + 1e-5f);
    #pragma unroll
    for (int ch = lane; ch < C; ch += 64) {
      float v = (olds[r * CP + ch] - mu) * rstd;
      out[(size_t)(r0 + r) * C + ch] = fmaf(v, g[ch], lb[ch]);
    }
  }
}

__global__ __launch_bounds__(256) void proj_ln_all(Params P) {
  __shared__ float olds[2304];  // max over stages: RB*(C+4) floats
  int bid = blockIdx.x;
  if (bid < 1024)      proj_stage<32, 65536>(P, 0, bid, olds);
  else if (bid < 1280) proj_stage<64, 8192>(P, 1, bid - 1024, olds);
  else if (bid < 1344) proj_stage<128, 1024>(P, 2, bid - 1280, olds);
  else                 proj_stage<256, 128>(P, 3, bid - 1344, olds);
}

extern "C" void kernel_launch(void* const* d_in, const int* in_sizes, int n_in,
                              void* d_out, int out_size, void* d_ws, size_t ws_size,
                              hipStream_t stream) {
  Params P;
  float* ws = (float*)d_ws;
  float* out = (float*)d_out;
  // ws layout (floats): packed K|V per stage, then split-K partial buffers
  const size_t kvoff[4]  = {0, 32768, 98304, 229376};
  const size_t A0 = 491520;                           // accP base (g=0 slice == attention output)
  const size_t rhbase[4] = {0, 131072, 163840, 172032};
  const size_t outoff[4] = {0, 2097152, 2621440, 2752512};

  int G = (ws_size >= (size_t)52101120) ? 4 : 1;      // partials need 52.1 MB; else fallback
  int KPG = 512 / G;
  float* accP = ws + A0;
  float* mP = accP + (size_t)G * 2785280;
  float* lP = mP + (size_t)G * RHTOT;

  for (int i = 0; i < 4; ++i) {
    const int b = i * 8;
    P.x[i]   = (const float*)d_in[b + 0];
    P.f[i]   = (const float*)d_in[b + 1];
    P.kvw[i] = (const float*)d_in[b + 2];
    P.kvb[i] = (const float*)d_in[b + 3];
    P.pw[i]  = (const float*)d_in[b + 4];
    P.pb[i]  = (const float*)d_in[b + 5];
    P.g[i]   = (const float*)d_in[b + 6];
    P.lb[i]  = (const float*)d_in[b + 7];
    P.kb[i]  = ws + kvoff[i];
    P.ob[i]  = accP + rhbase[i] * 16;                 // head-major [head][ROWS][16] slice
    P.out[i] = out + outoff[i];
  }

  copy_pass<<<6, 256, 0, stream>>>((const float4*)d_in[32], (const float4*)d_in[33],
                                   (float4*)(out + 2785280));
  kv_all<<<120, 256, 0, stream>>>(P);
  attn_split<<<352 * G, 256, 0, stream>>>(P.kb[0], P.kb[1], P.kb[2], P.kb[3],
                                          P.x[0], P.x[1], P.x[2], P.x[3],
                                          accP, mP, lP, G, KPG);
  if (G > 1) combine_k<<<680, 256, 0, stream>>>(accP, mP, lP, G);
  proj_ln_all<<<1360, 256, 0, stream>>>(P);
}

// Round 10
// 294.156 us; speedup vs baseline: 1.4294x; 1.2147x over previous
//
#include <hip/hip_runtime.h>

#define LOG2E 1.44269504088896340736f
#define RHTOT 174080

typedef float v4f __attribute__((ext_vector_type(4)));

struct Params {
  const float* x[4]; const float* f[4]; const float* kvw[4]; const float* kvb[4];
  const float* pw[4]; const float* pb[4]; const float* g[4]; const float* lb[4];
  float* kb[4]; float* out[4];
  const float4* cx4; const float4* cx5; float4* cout;
};

__device__ inline v4f fmav(float p, v4f b, v4f c) { return p * b + c; }
__device__ inline v4f fmav(v4f a, v4f b, v4f c) { return a * b + c; }

// ---------------- KV projection (+ passthrough copies in blocks 120..125) ----------------
__global__ __launch_bounds__(256) void kv_all(Params P) {
  int bid = blockIdx.x;
  if (bid >= 120) {  // passthrough x4/x5 (replaces SDMA memcpy nodes)
    int i = (bid - 120) * 256 + threadIdx.x;
    if (i < 1280)      P.cout[i] = P.cx4[i];
    else if (i < 1440) P.cout[i] = P.cx5[i - 1280];
    return;
  }
  int s, local;
  if (bid < 8)       { s = 0; local = bid; }
  else if (bid < 24) { s = 1; local = bid - 8; }
  else if (bid < 56) { s = 2; local = bid - 24; }
  else               { s = 3; local = bid - 56; }
  const int C = 32 << s;
  int nt = local & 7, jt = local >> 3;
  int n0 = nt * 64, j0 = jt * 64;
  const float* __restrict__ f = P.f[s];
  const float* __restrict__ w = P.kvw[s];
  __shared__ float fa[64][17];
  __shared__ float wb[64][17];
  int t = threadIdx.x;
  int ti = t & 15, tj = t >> 4;
  float acc[4][4];
  #pragma unroll
  for (int a = 0; a < 4; a++)
    #pragma unroll
    for (int b = 0; b < 4; b++) acc[a][b] = 0.f;

  for (int k0 = 0; k0 < C; k0 += 16) {
    __syncthreads();
    for (int i = t; i < 1024; i += 256) {
      int r = i >> 4, kk = i & 15;
      fa[r][kk] = f[(n0 + r) * C + k0 + kk];
      wb[r][kk] = w[(j0 + r) * C + k0 + kk];
    }
    __syncthreads();
    #pragma unroll
    for (int kk = 0; kk < 16; ++kk) {
      float av[4], bv[4];
      #pragma unroll
      for (int ii = 0; ii < 4; ii++) av[ii] = fa[ti * 4 + ii][kk];
      #pragma unroll
      for (int jj = 0; jj < 4; jj++) bv[jj] = wb[tj * 4 + jj][kk];
      #pragma unroll
      for (int ii = 0; ii < 4; ii++)
        #pragma unroll
        for (int jj = 0; jj < 4; jj++)
          acc[ii][jj] = fmaf(av[ii], bv[jj], acc[ii][jj]);
    }
  }
  const float* __restrict__ bias = P.kvb[s];
  float* kb = P.kb[s];
  #pragma unroll
  for (int ii = 0; ii < 4; ii++) {
    int n = n0 + ti * 4 + ii;
    #pragma unroll
    for (int jj = 0; jj < 4; jj++) {
      int j = j0 + tj * 4 + jj;
      float val = acc[ii][jj] + bias[j];
      if (j < C) {
        kb[(j >> 4) * 16384 + n * 32 + (j & 15)] = val;          // K slot
      } else {
        int j2 = j - C;
        kb[(j2 >> 4) * 16384 + n * 32 + 16 + (j2 & 15)] = val;   // V slot
      }
    }
  }
}

// ---------------- Attention split-K: 2 rows/lane, uniform K/V loads, EXPLICIT register double-buffer ----------------
// Buffer A holds key i while buffer B's loads for key i+1 are in flight (T14: issue-early/consume-late).
template <int C, int H, int ROWS, int RHB>
__device__ void attn_stage(const float* __restrict__ kb, const float* __restrict__ x,
                           float* __restrict__ accP, float* __restrict__ mP,
                           float* __restrict__ lP, int local, int G, int KPG) {
  int HG = H * G;
  int tile = local / HG, r2 = local % HG;
  int head = r2 / G, kg = r2 % G;
  int t = threadIdx.x;
  int row0 = tile * 512 + t;
  if (row0 >= ROWS) return;                      // stage-3 tail lanes
  int row1 = row0 + 256;
  bool v1 = row1 < ROWS;
  int rc1 = v1 ? row1 : (ROWS - 1);
  const v4f* __restrict__ kvh = (const v4f*)(kb + head * 16384 + (size_t)kg * KPG * 32);

  const float qs = 0.25f * LOG2E;                // head_dim^-0.5 folded with log2(e)
  const v4f* xa = (const v4f*)(x + (size_t)row0 * C + head * 16);
  const v4f* xb = (const v4f*)(x + (size_t)rc1 * C + head * 16);
  v4f qa0 = xa[0]*qs, qa1 = xa[1]*qs, qa2 = xa[2]*qs, qa3 = xa[3]*qs;
  v4f qb0 = xb[0]*qs, qb1 = xb[1]*qs, qb2 = xb[2]*qs, qb3 = xb[3]*qs;

  float ma = -1e30f, la = 0.f, mb = -1e30f, lb = 0.f;
  v4f aa0 = 0.f, aa1 = 0.f, aa2 = 0.f, aa3 = 0.f;
  v4f ab0 = 0.f, ab1 = 0.f, ab2 = 0.f, ab3 = 0.f;

  v4f A[8], B[8];  // constant-indexed only -> registers (rule #20)

#define LOADBUF(D, idx) do { const v4f* r_ = kvh + (size_t)(idx) * 8;          \
    D[0]=r_[0]; D[1]=r_[1]; D[2]=r_[2]; D[3]=r_[3];                            \
    D[4]=r_[4]; D[5]=r_[5]; D[6]=r_[6]; D[7]=r_[7]; } while (0)

#define STEP(Bf) do {                                                          \
    v4f ta = qa0*Bf[0]; ta = fmav(qa1,Bf[1],ta);                               \
    ta = fmav(qa2,Bf[2],ta); ta = fmav(qa3,Bf[3],ta);                          \
    v4f tb = qb0*Bf[0]; tb = fmav(qb1,Bf[1],tb);                               \
    tb = fmav(qb2,Bf[2],tb); tb = fmav(qb3,Bf[3],tb);                          \
    float sa = (ta.x + ta.y) + (ta.z + ta.w);   /* scores in log2 units */     \
    float sb = (tb.x + tb.y) + (tb.z + tb.w);                                  \
    if (__any(fmaxf(sa - ma, sb - mb) > 8.f)) { /* defer-max: rare */          \
      float mna = fmaxf(ma, sa);                                               \
      float ra = __builtin_amdgcn_exp2f(ma - mna);                             \
      la *= ra; aa0 *= ra; aa1 *= ra; aa2 *= ra; aa3 *= ra; ma = mna;          \
      float mnb = fmaxf(mb, sb);                                               \
      float rb = __builtin_amdgcn_exp2f(mb - mnb);                             \
      lb *= rb; ab0 *= rb; ab1 *= rb; ab2 *= rb; ab3 *= rb; mb = mnb;          \
    }                                                                          \
    float pa = __builtin_amdgcn_exp2f(sa - ma);                                \
    float pb = __builtin_amdgcn_exp2f(sb - mb);                                \
    la += pa; lb += pb;                                                        \
    aa0 = fmav(pa, Bf[4], aa0); aa1 = fmav(pa, Bf[5], aa1);                    \
    aa2 = fmav(pa, Bf[6], aa2); aa3 = fmav(pa, Bf[7], aa3);                    \
    ab0 = fmav(pb, Bf[4], ab0); ab1 = fmav(pb, Bf[5], ab1);                    \
    ab2 = fmav(pb, Bf[6], ab2); ab3 = fmav(pb, Bf[7], ab3); } while (0)

  LOADBUF(A, 0);
  #pragma unroll 1
  for (int key = 0; key < KPG; key += 2) {
    LOADBUF(B, key + 1);                         // in flight while computing A
    STEP(A);
    int nx = key + 2 < KPG ? key + 2 : 0;        // final iter: harmless dummy reload
    LOADBUF(A, nx);
    STEP(B);
  }
#undef LOADBUF
#undef STEP

  size_t rhA = (size_t)RHB + (size_t)head * ROWS + row0;
  size_t kgo = (size_t)kg * RHTOT;
  if (G == 1) {                                  // fallback path: normalize in-place, no combine
    float inv = 1.f / la;
    v4f* d = (v4f*)(accP + rhA * 16);
    d[0] = aa0 * inv; d[1] = aa1 * inv; d[2] = aa2 * inv; d[3] = aa3 * inv;
    if (v1) {
      float invb = 1.f / lb;
      v4f* e = (v4f*)(accP + ((size_t)RHB + (size_t)head * ROWS + row1) * 16);
      e[0] = ab0 * invb; e[1] = ab1 * invb; e[2] = ab2 * invb; e[3] = ab3 * invb;
    }
  } else {
    mP[kgo + rhA] = ma; lP[kgo + rhA] = la;
    v4f* d = (v4f*)(accP + (kgo + rhA) * 16);
    d[0] = aa0; d[1] = aa1; d[2] = aa2; d[3] = aa3;
    if (v1) {
      size_t rhB = (size_t)RHB + (size_t)head * ROWS + row1;
      mP[kgo + rhB] = mb; lP[kgo + rhB] = lb;
      v4f* e = (v4f*)(accP + (kgo + rhB) * 16);
      e[0] = ab0; e[1] = ab1; e[2] = ab2; e[3] = ab3;
    }
  }
}

__global__ __launch_bounds__(256) void attn_split(
    const float* __restrict__ kb0, const float* __restrict__ kb1,
    const float* __restrict__ kb2, const float* __restrict__ kb3,
    const float* __restrict__ x0, const float* __restrict__ x1,
    const float* __restrict__ x2, const float* __restrict__ x3,
    float* __restrict__ accP, float* __restrict__ mP, float* __restrict__ lP,
    int G, int KPG) {
  int bid = blockIdx.x;
  int b0 = 256 * G, b1 = b0 + 64 * G, b2 = b1 + 16 * G;
  if (bid < b0)      attn_stage<32, 2, 65536, 0>(kb0, x0, accP, mP, lP, bid, G, KPG);
  else if (bid < b1) attn_stage<64, 4, 8192, 131072>(kb1, x1, accP, mP, lP, bid - b0, G, KPG);
  else if (bid < b2) attn_stage<128, 8, 1024, 163840>(kb2, x2, accP, mP, lP, bid - b1, G, KPG);
  else               attn_stage<256, 16, 128, 172032>(kb3, x3, accP, mP, lP, bid - b2, G, KPG);
}

// ---------------- Proj + residual + LayerNorm, with fused split-K combine on the LDS fill ----------------
template <int C, int ROWS, int RHB>
__device__ void proj_stage(const Params& P, int s, int tile, float* olds,
                           const float* __restrict__ accP, const float* __restrict__ mP,
                           const float* __restrict__ lP, int G) {
  constexpr int CP = C + 4;      // +4 floats keeps 16B alignment, breaks bank aliasing
  constexpr int R = 256 / C;     // row-groups per pass
  constexpr int NR = 8;          // rows per thread
  constexpr int RB = 2048 / C;   // rows per block
  constexpr int RB4 = RB * 4;
  int r0 = tile * RB;
  int t = threadIdx.x;
  const float4* __restrict__ a4 = (const float4*)accP;
  for (int i = t; i < 512; i += 256) {
    int h = i / RB4, rem = i - h * RB4;
    int row = rem >> 2, d4 = rem & 3;
    size_t rh = (size_t)RHB + (size_t)h * ROWS + r0 + row;
    float4 o;
    if (G == 1) {
      o = a4[rh * 4 + d4];
    } else {                                     // combine split-K partials inline
      float M = mP[rh];
      for (int g = 1; g < G; ++g) M = fmaxf(M, mP[(size_t)g * RHTOT + rh]);
      float lt = 0.f;
      v4f acc = 0.f;
      for (int g = 0; g < G; ++g) {
        size_t idx = (size_t)g * RHTOT + rh;
        float w = __builtin_amdgcn_exp2f(mP[idx] - M);
        lt = fmaf(w, lP[idx], lt);
        v4f av = ((const v4f*)accP)[idx * 4 + d4];
        acc = fmav(w, av, acc);
      }
      float inv = 1.f / lt;
      o.x = acc.x * inv; o.y = acc.y * inv; o.z = acc.z * inv; o.w = acc.w * inv;
    }
    ((float4*)(olds + row * CP + h * 16))[d4] = o;
  }
  __syncthreads();
  int j = t % C, rg = t / C;
  const float* __restrict__ pw = P.pw[s];
  float acc[NR];
  #pragma unroll
  for (int i = 0; i < NR; ++i) acc[i] = 0.f;
  for (int k = 0; k < C; k += 4) {
    float4 w4 = *(const float4*)(pw + (size_t)j * C + k);
    #pragma unroll
    for (int i = 0; i < NR; ++i) {
      float4 o4 = *(const float4*)(olds + (rg + i * R) * CP + k);
      acc[i] = fmaf(o4.x, w4.x, acc[i]);
      acc[i] = fmaf(o4.y, w4.y, acc[i]);
      acc[i] = fmaf(o4.z, w4.z, acc[i]);
      acc[i] = fmaf(o4.w, w4.w, acc[i]);
    }
  }
  __syncthreads();  // all proj reads of olds done
  float pbj = P.pb[s][j];
  const float* __restrict__ x = P.x[s];
  #pragma unroll
  for (int i = 0; i < NR; ++i) {
    int r = rg + i * R;
    float xv = x[(size_t)(r0 + r) * C + j];
    olds[r * CP + j] = 0.5f * (acc[i] + pbj) + 0.5f * xv;
  }
  __syncthreads();
  // LayerNorm: one wave handles RB/4 rows
  int lane = t & 63, wv = t >> 6;
  const float* __restrict__ g = P.g[s];
  const float* __restrict__ lb = P.lb[s];
  float* __restrict__ out = P.out[s];
  #pragma unroll
  for (int rr = 0; rr < RB / 4; ++rr) {
    int r = wv * (RB / 4) + rr;
    float sum = 0.f, sq = 0.f;
    #pragma unroll
    for (int ch = lane; ch < C; ch += 64) {
      float v = olds[r * CP + ch];
      sum += v; sq = fmaf(v, v, sq);
    }
    #pragma unroll
    for (int o = 32; o; o >>= 1) { sum += __shfl_xor(sum, o); sq += __shfl_xor(sq, o); }
    float mu = sum * (1.f / C);
    float var = sq * (1.f / C) - mu * mu;
    float rstd = rsqrtf(var + 1e-5f);
    #pragma unroll
    for (int ch = lane; ch < C; ch += 64) {
      float v = (olds[r * CP + ch] - mu) * rstd;
      out[(size_t)(r0 + r) * C + ch] = fmaf(v, g[ch], lb[ch]);
    }
  }
}

__global__ __launch_bounds__(256) void proj_ln_all(Params P, const float* __restrict__ accP,
                                                   const float* __restrict__ mP,
                                                   const float* __restrict__ lP, int G) {
  __shared__ float olds[2304];  // max over stages: RB*(C+4) floats
  int bid = blockIdx.x;
  if (bid < 1024)      proj_stage<32, 65536, 0>(P, 0, bid, olds, accP, mP, lP, G);
  else if (bid < 1280) proj_stage<64, 8192, 131072>(P, 1, bid - 1024, olds, accP, mP, lP, G);
  else if (bid < 1344) proj_stage<128, 1024, 163840>(P, 2, bid - 1280, olds, accP, mP, lP, G);
  else                 proj_stage<256, 128, 172032>(P, 3, bid - 1344, olds, accP, mP, lP, G);
}

extern "C" void kernel_launch(void* const* d_in, const int* in_sizes, int n_in,
                              void* d_out, int out_size, void* d_ws, size_t ws_size,
                              hipStream_t stream) {
  Params P;
  float* ws = (float*)d_ws;
  float* out = (float*)d_out;
  // ws layout (floats): packed K|V per stage, then split-K partial buffers
  const size_t kvoff[4]  = {0, 32768, 98304, 229376};
  const size_t A0 = 491520;
  const size_t outoff[4] = {0, 2097152, 2621440, 2752512};

  int G = (ws_size >= (size_t)52101120) ? 4 : 1;      // partials need 52.1 MB; else fallback
  int KPG = 512 / G;
  float* accP = ws + A0;
  float* mP = accP + (size_t)G * 2785280;
  float* lP = mP + (size_t)G * RHTOT;

  for (int i = 0; i < 4; ++i) {
    const int b = i * 8;
    P.x[i]   = (const float*)d_in[b + 0];
    P.f[i]   = (const float*)d_in[b + 1];
    P.kvw[i] = (const float*)d_in[b + 2];
    P.kvb[i] = (const float*)d_in[b + 3];
    P.pw[i]  = (const float*)d_in[b + 4];
    P.pb[i]  = (const float*)d_in[b + 5];
    P.g[i]   = (const float*)d_in[b + 6];
    P.lb[i]  = (const float*)d_in[b + 7];
    P.kb[i]  = ws + kvoff[i];
    P.out[i] = out + outoff[i];
  }
  P.cx4 = (const float4*)d_in[32];
  P.cx5 = (const float4*)d_in[33];
  P.cout = (float4*)(out + 2785280);

  kv_all<<<126, 256, 0, stream>>>(P);
  attn_split<<<352 * G, 256, 0, stream>>>(P.kb[0], P.kb[1], P.kb[2], P.kb[3],
                                          P.x[0], P.x[1], P.x[2], P.x[3],
                                          accP, mP, lP, G, KPG);
  proj_ln_all<<<1360, 256, 0, stream>>>(P, accP, mP, lP, G);
}